// Round 1
// 4323.404 us; speedup vs baseline: 1.5181x; 1.5181x over previous
//
#include <hip/hip_runtime.h>
#include <cmath>

// Problem constants
#define B 32
#define T 512
#define D_IN 512
#define H 1024
#define NG 4096
#define L 4
#define D_OUT 512
#define RING 8

typedef _Float16 half8 __attribute__((ext_vector_type(8)));
typedef float    floatx4 __attribute__((ext_vector_type(4)));

// ---- workspace byte offsets ----
// Wpk: per (l,wg): [w][i 0..15][nt 0..3][lane 0..63][8 halves] = 256 KB -> 64 MB total
// Xt : [t][ktg 0..15][q][m 0..31][8 halves] fp16 tiled x     -> 16 MB
// Rt : [l][slot 0..7][ktg 0..31][q][m][8 halves] fp16 h ring -> 2 MB
// seq: int [L][64]  per-wg sequence numbers (seq = t+1 after publishing h(t))
#define OFF_WPK 0ull
#define OFF_XT  67108864ull
#define OFF_RT  83886080ull
#define OFF_FLG 86114304ull

__device__ __forceinline__ int slot(int t) { return (t + 1) & (RING - 1); }
__device__ __forceinline__ float sigf(float x) { return 1.f / (1.f + __expf(-x)); }
__device__ __forceinline__ float tanhfast(float x) { return 2.f / (1.f + __expf(-2.f * x)) - 1.f; }

// Infinity-Cache-coherent data path (bypass L1/L2)
__device__ __forceinline__ void ld16(half8& d, const char* p) {
    asm volatile("global_load_dwordx4 %0, %1, off sc0 sc1" : "=v"(d) : "v"(p));
}
// plain cached load (L2-friendly) for constant tiles (Xt)
__device__ __forceinline__ void ld16nc(half8& d, const char* p) {
    asm volatile("global_load_dwordx4 %0, %1, off" : "=v"(d) : "v"(p));
}
__device__ __forceinline__ void st16(char* p, half8 v) {
    asm volatile("global_store_dwordx4 %0, %1, off sc0 sc1" :: "v"(p), "v"(v));
}
__device__ __forceinline__ void ld4cv(int& d, const int* p) {
    asm volatile("global_load_dword %0, %1, off sc0 sc1" : "=v"(d) : "v"(p));
}
__device__ __forceinline__ void st4cv(int* p, int v) {
    asm volatile("global_store_dword %0, %1, off sc0 sc1" :: "v"(p), "v"(v));
}

// wave-parallel poll: lane i watches sp[0] (caller passes base+lane).
// One coalesced IC round trip checks all 64 producers. No RMW contention.
__device__ __forceinline__ void poll64(const int* sp, int target) {
    int v;
    for (;;) {
        ld4cv(v, sp);
        asm volatile("s_waitcnt vmcnt(0)" : "+v"(v));
        if (__all(v >= target)) return;
        __builtin_amdgcn_s_sleep(1);
    }
}

// ---------------------------------------------------------------------------
// pack_w: fp32 weights -> fp16 B-fragments for mfma_f32_16x16x32_f16.
// B-frag layout: lane holds B[k = ktg*32 + (lane>>4)*8 + j][n = nt*1024 + wg*16 + (lane&15)]
// ktg = i*4 + w (K interleaved across waves). l=0: k in [512,1024) is zero pad.
// ---------------------------------------------------------------------------
__global__ __launch_bounds__(256) void pack_w(
    const float* __restrict__ Wx0, const float* __restrict__ Wh0,
    const float* __restrict__ Wx,  const float* __restrict__ Wh,
    uint32_t* __restrict__ dst)
{
    unsigned g = blockIdx.x * 256u + threadIdx.x;        // < 16,777,216
    unsigned lwg = g >> 16;
    int l = lwg >> 6, wg = lwg & 63;
    unsigned s = g & 65535u;
    int w  = s >> 14, i = (s >> 10) & 15, nt = (s >> 8) & 3;
    int q  = (s >> 6) & 3, jp = (s >> 4) & 3, r = s & 15;
    int k  = (i * 4 + w) * 32 + q * 8 + jp * 2;
    int n  = nt * 1024 + wg * 16 + r;

    float a, bv;
    if (l == 0) {
        if (k < 512)       { a = Wx0[(size_t)k * NG + n]; bv = Wx0[(size_t)(k + 1) * NG + n]; }
        else if (k < 1024) { a = 0.f; bv = 0.f; }
        else               { a = Wh0[(size_t)(k - 1024) * NG + n]; bv = Wh0[(size_t)(k - 1023) * NG + n]; }
    } else {
        const float* src;
        if (k < 1024) src = Wx + (size_t)(l - 1) * H * NG;
        else          src = Wh + (size_t)(l - 1) * H * NG - (size_t)1024 * NG;
        a  = src[(size_t)k * NG + n];
        bv = src[(size_t)(k + 1) * NG + n];
    }
    union { _Float16 h[2]; uint32_t u; } cv;
    cv.h[0] = (_Float16)a; cv.h[1] = (_Float16)bv;
    dst[(size_t)lwg * 65536 + (((size_t)(w * 16 + i) * 4 + nt) * 64 + q * 16 + r) * 4 + jp] = cv.u;
}

// ---------------------------------------------------------------------------
// tile_x: x fp32 [B][T][D_IN] -> Xt fp16 tiled [t][ktg][q][m][8]
// ---------------------------------------------------------------------------
__global__ __launch_bounds__(256) void tile_x(const float* __restrict__ x,
                                              uint32_t* __restrict__ dst)
{
    unsigned g = blockIdx.x * 256u + threadIdx.x;        // < 4,194,304
    int jp = g & 3, m = (g >> 2) & 31, q = (g >> 7) & 3, ktg = (g >> 9) & 15, t = g >> 13;
    int k = ktg * 32 + q * 8 + jp * 2;
    const float* xp = x + (size_t)m * (T * D_IN) + (size_t)t * D_IN + k;
    union { _Float16 h[2]; uint32_t u; } cv;
    cv.h[0] = (_Float16)xp[0]; cv.h[1] = (_Float16)xp[1];
    dst[g] = cv.u;
}

// ---------------------------------------------------------------------------
// Persistent MFMA LSTM. 256 blocks (4 layers x 64 wgs) x 256 threads.
// Sync restructure vs prior version:
//  * per-wg seq numbers (plain release-ordered stores) replace the 64-way
//    atomic counter -> no IC RMW serialization per step
//  * wave-parallel polling (lane i watches wg i, __all) replaces tid0 relay
//  * step split: phase A (x / lower-h, K 0..1023; no own-h dep) runs BEFORE
//    the own-h wait; phase B (own h, K 1024..2047) after -> own-h publish
//    latency is overlapped by phase A compute
//  * 16 A-loads issued up front per phase, vmcnt(12/8/4/0) -> one exposed
//    IC latency per phase instead of ~2.7x with the old 3-deep rotation
//  * cond snapshots (v0/v2/v3) prefetched so satisfied-case waits are free
//  * ring-safety wait moved off the load path (wave 0, pre-publish)
//  * l==0 x loads are plain cached loads (Xt constant -> L2 hits) and the
//    zero-pad k-tiles 4..7 are skipped entirely
// ---------------------------------------------------------------------------
__global__ __launch_bounds__(256, 1) void lstm_mfma(
    const float* __restrict__ b0,
    const float* __restrict__ bb,
    const float* __restrict__ Wout,
    const float* __restrict__ bout,
    float* __restrict__ out,
    const char* __restrict__ WpkB,
    const char* __restrict__ XtB,
    char* __restrict__ RtB,
    int*   __restrict__ seq)
{
    __shared__ floatx4 red[2048];        // [w][mt][nt][lane][4f32] = 32 KB
    __shared__ _Float16 hsh[512];        // [m][u] 1 KB
    // + 56 KB dynamic LDS (unused) forces 1 block/CU

    const int tid  = threadIdx.x;
    const int l    = blockIdx.x >> 6;
    const int wg   = blockIdx.x & 63;
    const int lane = tid & 63;
    const int w    = tid >> 6;
    const int q    = lane >> 4;
    const int r    = lane & 15;
    const int laneoff = q * 512 + r * 16;

    // ---- one-time: B-fragments into registers ----
    half8 bfr[16][4];
    {
        const half8* wb = (const half8*)WpkB + (size_t)(l * 64 + wg) * 16384 + w * 4096 + lane;
        #pragma unroll
        for (int i = 0; i < 16; ++i)
            #pragma unroll
            for (int nt = 0; nt < 4; ++nt)
                bfr[i][nt] = wb[(i * 4 + nt) * 64];
    }
    // (l==0: bfr[4..7] are zeros from pack_w and unused now)

    // ---- biases + persistent cell state (update threads: tid<128) ----
    float bias4[4] = {0.f, 0.f, 0.f, 0.f};
    float cst[4]   = {0.f, 0.f, 0.f, 0.f};
    const float* biasl = (l == 0) ? b0 : (bb + (size_t)(l - 1) * NG);
    if (tid < 128) {
        #pragma unroll
        for (int g = 0; g < 4; ++g) bias4[g] = biasl[g * 1024 + wg * 16 + (tid & 15)];
    }

    const int* seqm1 = seq + (l - 1) * 64 + lane;   // valid only l>0
    const int* seq0  = seq + l * 64 + lane;
    const int* seqp1 = seq + (l + 1) * 64 + lane;   // valid only l<L-1

    // cond snapshots (prefetched; re-issued at end of each step)
    int v0 = 0, v2 = 0, v3 = 0;
    if (l > 0) ld4cv(v2, seqm1);   // v2 issued BEFORE v0 (older in vmcnt order)
    ld4cv(v0, seq0);

    #define ISSUE4(jj, base, LDF) do { \
        const char* p0_ = (base) + (2*(jj)) * 8192; \
        const char* p1_ = (base) + (2*(jj)+1) * 8192; \
        LDF(ab[jj][0], p0_); LDF(ab[jj][1], p0_ + 256); \
        LDF(ab[jj][2], p1_); LDF(ab[jj][3], p1_ + 256); \
    } while (0)

    #define WAITV(N, jj) asm volatile("s_waitcnt vmcnt(" #N ")" \
        : "+v"(ab[jj][0]), "+v"(ab[jj][1]), "+v"(ab[jj][2]), "+v"(ab[jj][3]))

    #define MFMA4(jj, bi) do { \
        _Pragma("unroll") \
        for (int nt = 0; nt < 4; ++nt) { \
            acc[0][nt] = __builtin_amdgcn_mfma_f32_16x16x32_f16(ab[jj][0], bfr[(bi)][nt],   acc[0][nt], 0, 0, 0); \
            acc[1][nt] = __builtin_amdgcn_mfma_f32_16x16x32_f16(ab[jj][1], bfr[(bi)][nt],   acc[1][nt], 0, 0, 0); \
            acc[0][nt] = __builtin_amdgcn_mfma_f32_16x16x32_f16(ab[jj][2], bfr[(bi)+1][nt], acc[0][nt], 0, 0, 0); \
            acc[1][nt] = __builtin_amdgcn_mfma_f32_16x16x32_f16(ab[jj][3], bfr[(bi)+1][nt], acc[1][nt], 0, 0, 0); \
        } \
    } while (0)

    for (int t = 0; t < T; ++t) {
        half8 ab[4][4];
        floatx4 acc[2][4];
        #pragma unroll
        for (int mt = 0; mt < 2; ++mt)
            #pragma unroll
            for (int nt = 0; nt < 4; ++nt) acc[mt][nt] = (floatx4)0.f;

        // ---------- phase A: input half (no own-h dependency) ----------
        if (l == 0) {
            // Xt is constant (written by tile_x before launch): cached loads.
            // k-tiles 4..7 are the zero pad -> skipped entirely.
            const char* axb = XtB + (size_t)t * 32768 + w * 2048 + laneoff;
            ISSUE4(0, axb, ld16nc); ISSUE4(1, axb, ld16nc);
            WAITV(4, 0); MFMA4(0, 0);
            WAITV(0, 1); MFMA4(1, 2);
        } else {
            // cond2: lower layer published h(t). Snapshot first (vmcnt(1)
            // keeps v0 in flight); ring slack keeps this satisfied in steady
            // state, so the fast path costs zero extra round trips.
            asm volatile("s_waitcnt vmcnt(1)" : "+v"(v2));
            if (!__all(v2 >= t + 1)) poll64(seqm1, t + 1);
            const char* axb = RtB + (size_t)((l - 1) * 8 + slot(t)) * 65536 + w * 2048 + laneoff;
            ISSUE4(0, axb, ld16); ISSUE4(1, axb, ld16);
            ISSUE4(2, axb, ld16); ISSUE4(3, axb, ld16);
            WAITV(12, 0); MFMA4(0, 0);
            WAITV(8, 1);  MFMA4(1, 2);
            WAITV(4, 2);  MFMA4(2, 4);
            WAITV(0, 3);  MFMA4(3, 6);
        }

        // ---------- phase B: own-h half (the real recurrence wait) ----------
        asm volatile("s_waitcnt vmcnt(0)" : "+v"(v0));
        if (!__all(v0 >= t)) poll64(seq0, t);
        {
            const char* ahb = RtB + (size_t)(l * 8 + slot(t - 1)) * 65536 + w * 2048 + laneoff;
            ISSUE4(0, ahb, ld16); ISSUE4(1, ahb, ld16);
            ISSUE4(2, ahb, ld16); ISSUE4(3, ahb, ld16);
            WAITV(12, 0); MFMA4(0, 8);
            WAITV(8, 1);  MFMA4(1, 10);
            WAITV(4, 2);  MFMA4(2, 12);
            WAITV(0, 3);  MFMA4(3, 14);
        }

        // ---- cross-wave reduce via LDS ----
        #pragma unroll
        for (int mt = 0; mt < 2; ++mt)
            #pragma unroll
            for (int nt = 0; nt < 4; ++nt)
                red[((w * 2 + mt) * 4 + nt) * 64 + lane] = acc[mt][nt];

        // prefetch ring-safety snapshot (consumed by wave 0 pre-publish)
        if (l < L - 1 && tid < 64) ld4cv(v3, seqp1);
        __syncthreads();

        // ---- gate sums + cell update (threads 0..127) ----
        if (tid < 128) {
            const int u = tid & 15, mq = tid >> 4, mt = mq >> 2, qq = mq & 3;
            const int lp = qq * 16 + u;
            floatx4 s0 = (floatx4)0.f, s1 = (floatx4)0.f, s2 = (floatx4)0.f, s3 = (floatx4)0.f;
            #pragma unroll
            for (int w2 = 0; w2 < 4; ++w2) {
                s0 += red[((w2 * 2 + mt) * 4 + 0) * 64 + lp];
                s1 += red[((w2 * 2 + mt) * 4 + 1) * 64 + lp];
                s2 += red[((w2 * 2 + mt) * 4 + 2) * 64 + lp];
                s3 += red[((w2 * 2 + mt) * 4 + 3) * 64 + lp];
            }
            #pragma unroll
            for (int rr = 0; rr < 4; ++rr) {
                float gi = s0[rr] + bias4[0];
                float gf = s1[rr] + bias4[1];
                float gg = s2[rr] + bias4[2];
                float go = s3[rr] + bias4[3];
                float cn = sigf(gf) * cst[rr] + sigf(gi) * tanhfast(gg);
                cst[rr] = cn;
                float hv = sigf(go) * tanhfast(cn);
                int m = mt * 16 + qq * 4 + rr;
                hsh[m * 16 + u] = (_Float16)hv;
            }
        }
        __syncthreads();

        // ---- publish h(t) write-through (wave 0), drain, seq store ----
        if (tid < 64) {
            if (l < L - 1) {
                // ring safety: don't overwrite h(t-RING) before layer l+1
                // consumed it. Snapshot was prefetched before barrier 1.
                asm volatile("s_waitcnt vmcnt(0)" : "+v"(v3));
                if (t >= RING && !__all(v3 >= t - RING + 1)) poll64(seqp1, t - RING + 1);
            }
            int m = tid & 31, uq = tid >> 5;
            half8 hv = *(const half8*)&hsh[m * 16 + uq * 8];
            char* dst = RtB + (size_t)(l * 8 + slot(t)) * 65536
                        + (wg >> 1) * 2048 + ((wg & 1) * 2 + uq) * 512 + m * 16;
            st16(dst, hv);
            asm volatile("s_waitcnt vmcnt(0)");   // h stores acked at IC
            if (tid == 0) st4cv(seq + l * 64 + wg, t + 1);
        }

        // re-issue cond snapshots for next step (v2 before v0: vmcnt order)
        if (l > 0) ld4cv(v2, seqm1);
        ld4cv(v0, seq0);
    }

    #undef ISSUE4
    #undef WAITV
    #undef MFMA4

    // ---- output projection (layer-0 blocks) ----
    if (l != 0) return;
    if (tid < 64) poll64(seq + (L - 1) * 64 + lane, T);
    __syncthreads();

    const int b  = blockIdx.x >> 1;
    const int o0 = (blockIdx.x & 1) << 8;
    const char* rt3 = RtB + (size_t)((L - 1) * 8 + slot(T - 1)) * 65536;
    float* hb = (float*)red;
    if (tid < 128) {
        int j0 = tid * 8;
        half8 hv;
        ld16(hv, rt3 + ((j0 >> 5) * 2048 + ((j0 >> 3) & 3) * 512 + b * 16));
        asm volatile("s_waitcnt vmcnt(0)" : "+v"(hv));
        #pragma unroll
        for (int k2 = 0; k2 < 8; ++k2) hb[j0 + k2] = (float)hv[k2];
    }
    __syncthreads();
    const int o = o0 + tid;
    float s = bout[o];
    #pragma unroll 8
    for (int j = 0; j < H; ++j)
        s += hb[j] * Wout[(size_t)j * D_OUT + o];
    out[(size_t)b * D_OUT + o] = s;
}

extern "C" void kernel_launch(void* const* d_in, const int* in_sizes, int n_in,
                              void* d_out, int out_size, void* d_ws, size_t ws_size,
                              hipStream_t stream) {
    const float* x    = (const float*)d_in[0];
    const float* Wx0  = (const float*)d_in[1];
    const float* Wh0  = (const float*)d_in[2];
    const float* b0   = (const float*)d_in[3];
    const float* Wx   = (const float*)d_in[4];
    const float* Wh   = (const float*)d_in[5];
    const float* bb   = (const float*)d_in[6];
    const float* Wout = (const float*)d_in[7];
    const float* bout = (const float*)d_in[8];
    float* out = (float*)d_out;

    char* ws = (char*)d_ws;
    uint32_t* Wpk  = (uint32_t*)(ws + OFF_WPK);
    uint32_t* Xt   = (uint32_t*)(ws + OFF_XT);
    char*     Rt   = ws + OFF_RT;
    int*      seq  = (int*)(ws + OFF_FLG);

    hipMemsetAsync(Rt, 0, 2097152, stream);              // h(-1) = 0
    hipMemsetAsync(seq, 0, L * 64 * sizeof(int), stream);

    pack_w<<<dim3(65536), dim3(256), 0, stream>>>(Wx0, Wh0, Wx, Wh, Wpk);
    tile_x<<<dim3(16384), dim3(256), 0, stream>>>(x, Xt);

    hipFuncSetAttribute(reinterpret_cast<const void*>(&lstm_mfma),
                        hipFuncAttributeMaxDynamicSharedMemorySize, 57344);
    lstm_mfma<<<dim3(256), dim3(256), 57344, stream>>>(
        b0, bb, Wout, bout, out, (const char*)Wpk, (const char*)Xt, Rt, seq);
}

// Round 3
// 3643.336 us; speedup vs baseline: 1.8014x; 1.1867x over previous
//
#include <hip/hip_runtime.h>
#include <cmath>

// Problem constants
#define B 32
#define T 512
#define D_IN 512
#define H 1024
#define NG 4096
#define L 4
#define D_OUT 512
#define RING 8

typedef _Float16 half8 __attribute__((ext_vector_type(8)));
typedef float    floatx4 __attribute__((ext_vector_type(4)));

// ---- workspace byte offsets ----
// Wpk: per (l,wg): [w][i 0..15][nt 0..3][lane 0..63][8 halves] = 256 KB -> 64 MB total
// Xt : [t][ktg 0..15][q][m 0..31][8 halves] fp16 tiled x     -> 16 MB
// Rt : [l][slot 0..7][ktg 0..31][q][m][8 halves] fp16 h ring -> 2 MB
// seq: int [L][64]  per-wg sequence numbers (seq = t+1 after h(t) published)
#define OFF_WPK 0ull
#define OFF_XT  67108864ull
#define OFF_RT  83886080ull
#define OFF_FLG 86114304ull

__device__ __forceinline__ int slot(int t) { return (t + 1) & (RING - 1); }
__device__ __forceinline__ float sigf(float x) { return 1.f / (1.f + __expf(-x)); }
__device__ __forceinline__ float tanhfast(float x) { return 2.f / (1.f + __expf(-2.f * x)) - 1.f; }

// Infinity-Cache-coherent data path (bypass L1/L2)
__device__ __forceinline__ void ld16(half8& d, const char* p) {
    asm volatile("global_load_dwordx4 %0, %1, off sc0 sc1" : "=v"(d) : "v"(p));
}
// plain cached load (L2-friendly) for constant tiles (Xt)
__device__ __forceinline__ void ld16nc(half8& d, const char* p) {
    asm volatile("global_load_dwordx4 %0, %1, off" : "=v"(d) : "v"(p));
}
__device__ __forceinline__ void st16(char* p, half8 v) {
    asm volatile("global_store_dwordx4 %0, %1, off sc0 sc1" :: "v"(p), "v"(v));
}
__device__ __forceinline__ void st2(char* p, int v) {
    asm volatile("global_store_short %0, %1, off sc0 sc1" :: "v"(p), "v"(v));
}
__device__ __forceinline__ void ld4cv(int& d, const int* p) {
    asm volatile("global_load_dword %0, %1, off sc0 sc1" : "=v"(d) : "v"(p));
}
__device__ __forceinline__ void st4cv(int* p, int v) {
    asm volatile("global_store_dword %0, %1, off sc0 sc1" :: "v"(p), "v"(v));
}

// wave-parallel poll: lane i watches sp[0] (caller passes base+lane).
// Only wave 0 (or update waves for the rare ring check) runs this now.
__device__ __forceinline__ void poll64(const int* sp, int target) {
    int v;
    for (;;) {
        ld4cv(v, sp);
        asm volatile("s_waitcnt vmcnt(0)" : "+v"(v));
        if (__all(v >= target)) return;
        __builtin_amdgcn_s_sleep(2);
    }
}

// ---------------------------------------------------------------------------
// pack_w: fp32 weights -> fp16 B-fragments for mfma_f32_16x16x32_f16.
// B-frag layout: lane holds B[k = ktg*32 + (lane>>4)*8 + j][n = nt*1024 + wg*16 + (lane&15)]
// ktg = i*4 + w (K interleaved across waves). l=0: k in [512,1024) is zero pad.
// ---------------------------------------------------------------------------
__global__ __launch_bounds__(256) void pack_w(
    const float* __restrict__ Wx0, const float* __restrict__ Wh0,
    const float* __restrict__ Wx,  const float* __restrict__ Wh,
    uint32_t* __restrict__ dst)
{
    unsigned g = blockIdx.x * 256u + threadIdx.x;        // < 16,777,216
    unsigned lwg = g >> 16;
    int l = lwg >> 6, wg = lwg & 63;
    unsigned s = g & 65535u;
    int w  = s >> 14, i = (s >> 10) & 15, nt = (s >> 8) & 3;
    int q  = (s >> 6) & 3, jp = (s >> 4) & 3, r = s & 15;
    int k  = (i * 4 + w) * 32 + q * 8 + jp * 2;
    int n  = nt * 1024 + wg * 16 + r;

    float a, bv;
    if (l == 0) {
        if (k < 512)       { a = Wx0[(size_t)k * NG + n]; bv = Wx0[(size_t)(k + 1) * NG + n]; }
        else if (k < 1024) { a = 0.f; bv = 0.f; }
        else               { a = Wh0[(size_t)(k - 1024) * NG + n]; bv = Wh0[(size_t)(k - 1023) * NG + n]; }
    } else {
        const float* src;
        if (k < 1024) src = Wx + (size_t)(l - 1) * H * NG;
        else          src = Wh + (size_t)(l - 1) * H * NG - (size_t)1024 * NG;
        a  = src[(size_t)k * NG + n];
        bv = src[(size_t)(k + 1) * NG + n];
    }
    union { _Float16 h[2]; uint32_t u; } cv;
    cv.h[0] = (_Float16)a; cv.h[1] = (_Float16)bv;
    dst[(size_t)lwg * 65536 + (((size_t)(w * 16 + i) * 4 + nt) * 64 + q * 16 + r) * 4 + jp] = cv.u;
}

// ---------------------------------------------------------------------------
// tile_x: x fp32 [B][T][D_IN] -> Xt fp16 tiled [t][ktg][q][m][8]
// ---------------------------------------------------------------------------
__global__ __launch_bounds__(256) void tile_x(const float* __restrict__ x,
                                              uint32_t* __restrict__ dst)
{
    unsigned g = blockIdx.x * 256u + threadIdx.x;        // < 4,194,304
    int jp = g & 3, m = (g >> 2) & 31, q = (g >> 7) & 3, ktg = (g >> 9) & 15, t = g >> 13;
    int k = ktg * 32 + q * 8 + jp * 2;
    const float* xp = x + (size_t)m * (T * D_IN) + (size_t)t * D_IN + k;
    union { _Float16 h[2]; uint32_t u; } cv;
    cv.h[0] = (_Float16)xp[0]; cv.h[1] = (_Float16)xp[1];
    dst[g] = cv.u;
}

// ---------------------------------------------------------------------------
// Persistent MFMA LSTM. 256 blocks (4 layers x 64 wgs) x 256 threads.
// R3: R1-proven seq protocol (drain-then-flag, check-then-load; every
// ordering-critical drain is a FULL vmcnt(0); counted waits only feed
// checks with conservative poll fallback). Changes vs R1:
//  * wave-0-only gating + barrier release for phase A/B waits: poll and
//    snapshot traffic /4 (the R1 poll storm inflated IC RT ~3x)
//  * poll backoff s_sleep(2)
//  * direct-store publish: update threads (waves 0,1) store h straight to
//    the ring as computed (global_store_short x4/thread), per-wave
//    vmcnt(0) full drain, barrier, then tid0 seq store. Removes the hsh
//    LDS hop + wave0 republish; store-ack starts ~0.3us earlier.
//  * ring-safety check moved to update waves, pre-store (same bound)
// ---------------------------------------------------------------------------
__global__ __launch_bounds__(256, 1) void lstm_mfma(
    const float* __restrict__ b0,
    const float* __restrict__ bb,
    const float* __restrict__ Wout,
    const float* __restrict__ bout,
    float* __restrict__ out,
    const char* __restrict__ WpkB,
    const char* __restrict__ XtB,
    char* __restrict__ RtB,
    int*   __restrict__ seq)
{
    __shared__ floatx4 red[2048];        // [w][mt][nt][lane][4f32] = 32 KB
    // + 56 KB dynamic LDS (unused) forces 1 block/CU

    const int tid  = threadIdx.x;
    const int l    = blockIdx.x >> 6;
    const int wg   = blockIdx.x & 63;
    const int lane = tid & 63;
    const int w    = tid >> 6;
    const int q    = lane >> 4;
    const int r    = lane & 15;
    const int laneoff = q * 512 + r * 16;

    // ---- one-time: B-fragments into registers ----
    half8 bfr[16][4];
    {
        const half8* wb = (const half8*)WpkB + (size_t)(l * 64 + wg) * 16384 + w * 4096 + lane;
        #pragma unroll
        for (int i = 0; i < 16; ++i)
            #pragma unroll
            for (int nt = 0; nt < 4; ++nt)
                bfr[i][nt] = wb[(i * 4 + nt) * 64];
    }
    // l==0: bfr[4..7] are zeros from pack_w and unused (pad tiles skipped)

    // ---- biases + persistent cell state (update threads: tid<128) ----
    float bias4[4] = {0.f, 0.f, 0.f, 0.f};
    float cst[4]   = {0.f, 0.f, 0.f, 0.f};
    const float* biasl = (l == 0) ? b0 : (bb + (size_t)(l - 1) * NG);
    if (tid < 128) {
        #pragma unroll
        for (int g = 0; g < 4; ++g) bias4[g] = biasl[g * 1024 + wg * 16 + (tid & 15)];
    }

    const int* seqm1 = seq + (l - 1) * 64 + lane;   // valid only l>0
    const int* seq0  = seq + l * 64 + lane;
    const int* seqp1 = seq + (l + 1) * 64 + lane;   // valid only l<L-1

    // cond snapshots: v2/v0 only by wave 0; v3 by update waves (0,1)
    int v0 = 0, v2 = 0, v3 = 0;
    if (tid < 64) {
        if (l > 0) ld4cv(v2, seqm1);   // queue [v2, v0]: consume v2 @ vmcnt(1)
        ld4cv(v0, seq0);
    }

    #define ISSUE4(jj, base, LDF) do { \
        const char* p0_ = (base) + (2*(jj)) * 8192; \
        const char* p1_ = (base) + (2*(jj)+1) * 8192; \
        LDF(ab[jj][0], p0_); LDF(ab[jj][1], p0_ + 256); \
        LDF(ab[jj][2], p1_); LDF(ab[jj][3], p1_ + 256); \
    } while (0)

    #define WAITV(N, jj) asm volatile("s_waitcnt vmcnt(" #N ")" \
        : "+v"(ab[jj][0]), "+v"(ab[jj][1]), "+v"(ab[jj][2]), "+v"(ab[jj][3]))

    #define MFMA4(jj, bi) do { \
        _Pragma("unroll") \
        for (int nt = 0; nt < 4; ++nt) { \
            acc[0][nt] = __builtin_amdgcn_mfma_f32_16x16x32_f16(ab[jj][0], bfr[(bi)][nt],   acc[0][nt], 0, 0, 0); \
            acc[1][nt] = __builtin_amdgcn_mfma_f32_16x16x32_f16(ab[jj][1], bfr[(bi)][nt],   acc[1][nt], 0, 0, 0); \
            acc[0][nt] = __builtin_amdgcn_mfma_f32_16x16x32_f16(ab[jj][2], bfr[(bi)+1][nt], acc[0][nt], 0, 0, 0); \
            acc[1][nt] = __builtin_amdgcn_mfma_f32_16x16x32_f16(ab[jj][3], bfr[(bi)+1][nt], acc[1][nt], 0, 0, 0); \
        } \
    } while (0)

    for (int t = 0; t < T; ++t) {
        half8 ab[4][4];
        floatx4 acc[2][4];
        #pragma unroll
        for (int mt = 0; mt < 2; ++mt)
            #pragma unroll
            for (int nt = 0; nt < 4; ++nt) acc[mt][nt] = (floatx4)0.f;

        // ---------- phase A: input half (no own-h dependency) ----------
        if (l == 0) {
            // Xt constant -> plain cached loads; zero-pad k-tiles skipped.
            const char* axb = XtB + (size_t)t * 32768 + w * 2048 + laneoff;
            ISSUE4(0, axb, ld16nc); ISSUE4(1, axb, ld16nc);
            WAITV(4, 0); MFMA4(0, 0);
            WAITV(0, 1); MFMA4(1, 2);
        } else {
            // gate: lower layer published h(t). Wave 0 checks snapshot
            // (conservative on misfire -> poll), barrier releases the rest.
            if (tid < 64) {
                asm volatile("s_waitcnt vmcnt(1)" : "+v"(v2));
                if (!__all(v2 >= t + 1)) poll64(seqm1, t + 1);
            }
            __syncthreads();
            const char* axb = RtB + (size_t)((l - 1) * 8 + slot(t)) * 65536 + w * 2048 + laneoff;
            ISSUE4(0, axb, ld16); ISSUE4(1, axb, ld16);
            ISSUE4(2, axb, ld16); ISSUE4(3, axb, ld16);
            WAITV(12, 0); MFMA4(0, 0);
            WAITV(8, 1);  MFMA4(1, 2);
            WAITV(4, 2);  MFMA4(2, 4);
            WAITV(0, 3);  MFMA4(3, 6);
        }

        // ---------- phase B: own-h half (the recurrence wait) ----------
        if (tid < 64) {
            asm volatile("s_waitcnt vmcnt(0)" : "+v"(v0));
            if (!__all(v0 >= t)) poll64(seq0, t);
        }
        __syncthreads();
        {
            const char* ahb = RtB + (size_t)(l * 8 + slot(t - 1)) * 65536 + w * 2048 + laneoff;
            ISSUE4(0, ahb, ld16); ISSUE4(1, ahb, ld16);
            ISSUE4(2, ahb, ld16); ISSUE4(3, ahb, ld16);
            WAITV(12, 0); MFMA4(0, 8);
            WAITV(8, 1);  MFMA4(1, 10);
            WAITV(4, 2);  MFMA4(2, 12);
            WAITV(0, 3);  MFMA4(3, 14);
        }

        // ---- cross-wave reduce via LDS ----
        #pragma unroll
        for (int mt = 0; mt < 2; ++mt)
            #pragma unroll
            for (int nt = 0; nt < 4; ++nt)
                red[((w * 2 + mt) * 4 + nt) * 64 + lane] = acc[mt][nt];

        // prefetch ring-safety snapshot (consumed by update waves pre-store)
        if (l < L - 1 && tid < 128) ld4cv(v3, seqp1);
        __syncthreads();

        // ---- gate sums + cell update + DIRECT h publish (threads 0..127) ----
        if (tid < 128) {
            if (l < L - 1) {
                // slot(t) still holds h(t-8); layer l+1 must be past phase A
                // of step t-8, i.e. seq_{l+1} >= t-RING+1. Snapshot is ~t-1
                // in steady state -> poll essentially never runs.
                asm volatile("s_waitcnt vmcnt(0)" : "+v"(v3));
                if (t >= RING && !__all(v3 >= t - RING + 1)) poll64(seqp1, t - RING + 1);
            }
            const int u = tid & 15, mq = (tid >> 4) & 7, mt = mq >> 2, qq = mq & 3;
            const int lp = qq * 16 + u;
            floatx4 s0 = (floatx4)0.f, s1 = (floatx4)0.f, s2 = (floatx4)0.f, s3 = (floatx4)0.f;
            #pragma unroll
            for (int w2 = 0; w2 < 4; ++w2) {
                s0 += red[((w2 * 2 + mt) * 4 + 0) * 64 + lp];
                s1 += red[((w2 * 2 + mt) * 4 + 1) * 64 + lp];
                s2 += red[((w2 * 2 + mt) * 4 + 2) * 64 + lp];
                s3 += red[((w2 * 2 + mt) * 4 + 3) * 64 + lp];
            }
            // h[m][u] -> ring byte: K=wg>>1 (*2048), Q=(wg&1)*2+(u>>3) (*512),
            // m*16, (u&7)*2  (verified identical to R1's st16 layout)
            char* hp = RtB + (size_t)(l * 8 + slot(t)) * 65536
                     + (size_t)(wg >> 1) * 2048 + ((wg & 1) * 2 + (u >> 3)) * 512
                     + (u & 7) * 2;
            #pragma unroll
            for (int rr = 0; rr < 4; ++rr) {
                float gi = s0[rr] + bias4[0];
                float gf = s1[rr] + bias4[1];
                float gg = s2[rr] + bias4[2];
                float go = s3[rr] + bias4[3];
                float cn = sigf(gf) * cst[rr] + sigf(gi) * tanhfast(gg);
                cst[rr] = cn;
                float hv = sigf(go) * tanhfast(cn);
                int m = mt * 16 + qq * 4 + rr;
                union { _Float16 h; unsigned short s; } cvh; cvh.h = (_Float16)hv;
                st2(hp + m * 16, (int)cvh.s);
            }
            // full drain (pure vmcnt(0) = proven ordering primitive):
            // this wave's h stores are acked at the coherence point.
            asm volatile("s_waitcnt vmcnt(0)");
        }
        __syncthreads();   // both update waves drained before the flag

        // ---- publish flag + re-snapshot (wave 0) ----
        if (tid == 0) st4cv(seq + l * 64 + wg, t + 1);
        if (tid < 64) {
            if (l > 0) ld4cv(v2, seqm1);   // queue [seqst, v2, v0]
            ld4cv(v0, seq0);
        }
    }

    #undef ISSUE4
    #undef WAITV
    #undef MFMA4

    // ---- output projection (layer-0 blocks) ----
    if (l != 0) return;
    if (tid < 64) poll64(seq + (L - 1) * 64 + lane, T);
    __syncthreads();

    const int b  = blockIdx.x >> 1;
    const int o0 = (blockIdx.x & 1) << 8;
    const char* rt3 = RtB + (size_t)((L - 1) * 8 + slot(T - 1)) * 65536;
    float* hb = (float*)red;
    if (tid < 128) {
        int j0 = tid * 8;
        half8 hv;
        ld16(hv, rt3 + ((j0 >> 5) * 2048 + ((j0 >> 3) & 3) * 512 + b * 16));
        asm volatile("s_waitcnt vmcnt(0)" : "+v"(hv));
        #pragma unroll
        for (int k2 = 0; k2 < 8; ++k2) hb[j0 + k2] = (float)hv[k2];
    }
    __syncthreads();
    const int o = o0 + tid;
    float s = bout[o];
    #pragma unroll 8
    for (int j = 0; j < H; ++j)
        s += hb[j] * Wout[(size_t)j * D_OUT + o];
    out[(size_t)b * D_OUT + o] = s;
}

extern "C" void kernel_launch(void* const* d_in, const int* in_sizes, int n_in,
                              void* d_out, int out_size, void* d_ws, size_t ws_size,
                              hipStream_t stream) {
    const float* x    = (const float*)d_in[0];
    const float* Wx0  = (const float*)d_in[1];
    const float* Wh0  = (const float*)d_in[2];
    const float* b0   = (const float*)d_in[3];
    const float* Wx   = (const float*)d_in[4];
    const float* Wh   = (const float*)d_in[5];
    const float* bb   = (const float*)d_in[6];
    const float* Wout = (const float*)d_in[7];
    const float* bout = (const float*)d_in[8];
    float* out = (float*)d_out;

    char* ws = (char*)d_ws;
    uint32_t* Wpk  = (uint32_t*)(ws + OFF_WPK);
    uint32_t* Xt   = (uint32_t*)(ws + OFF_XT);
    char*     Rt   = ws + OFF_RT;
    int*      seq  = (int*)(ws + OFF_FLG);

    hipMemsetAsync(Rt, 0, 2097152, stream);              // h(-1) = 0
    hipMemsetAsync(seq, 0, L * 64 * sizeof(int), stream);

    pack_w<<<dim3(65536), dim3(256), 0, stream>>>(Wx0, Wh0, Wx, Wh, Wpk);
    tile_x<<<dim3(16384), dim3(256), 0, stream>>>(x, Xt);

    hipFuncSetAttribute(reinterpret_cast<const void*>(&lstm_mfma),
                        hipFuncAttributeMaxDynamicSharedMemorySize, 57344);
    lstm_mfma<<<dim3(256), dim3(256), 57344, stream>>>(
        b0, bb, Wout, bout, out, (const char*)Wpk, (const char*)Xt, Rt, seq);
}

// Round 6
// 2686.901 us; speedup vs baseline: 2.4427x; 1.3560x over previous
//
#include <hip/hip_runtime.h>
#include <cmath>

// Problem constants
#define B 32
#define T 512
#define D_IN 512
#define H 1024
#define NG 4096
#define L 4
#define D_OUT 512
#define RING 8

typedef _Float16 half8 __attribute__((ext_vector_type(8)));
typedef float    floatx4 __attribute__((ext_vector_type(4)));

// ---- workspace byte offsets ----
// Wpk: per (l,wg): [w][i 0..15][nt 0..3][lane 0..63][8 halves] = 256 KB -> 64 MB total
// Xt : [t][ktg 0..15][q][m 0..31][8 halves] fp16 tiled x     -> 16 MB
// Rt : [l][slot 0..7][ktg 0..31][q][m][8 halves] fp16 h ring -> 2 MB
// seq: int [L][64]  per-wg sequence numbers (seq = t+1 after h(t) published)
#define OFF_WPK 0ull
#define OFF_XT  67108864ull
#define OFF_RT  83886080ull
#define OFF_FLG 86114304ull

__device__ __forceinline__ int slot(int t) { return (t + 1) & (RING - 1); }
__device__ __forceinline__ float sigf(float x) { return 1.f / (1.f + __expf(-x)); }
__device__ __forceinline__ float tanhfast(float x) { return 2.f / (1.f + __expf(-2.f * x)) - 1.f; }

// Infinity-Cache-coherent data path (bypass L1/L2)
__device__ __forceinline__ void ld16(half8& d, const char* p) {
    asm volatile("global_load_dwordx4 %0, %1, off sc0 sc1" : "=v"(d) : "v"(p));
}
// plain cached load (L2-friendly) for constant tiles (Xt)
__device__ __forceinline__ void ld16nc(half8& d, const char* p) {
    asm volatile("global_load_dwordx4 %0, %1, off" : "=v"(d) : "v"(p));
}
__device__ __forceinline__ void st2(char* p, int v) {
    asm volatile("global_store_short %0, %1, off sc0 sc1" :: "v"(p), "v"(v));
}
__device__ __forceinline__ void ld4cv(int& d, const int* p) {
    asm volatile("global_load_dword %0, %1, off sc0 sc1" : "=v"(d) : "v"(p));
}
__device__ __forceinline__ void st4cv(int* p, int v) {
    asm volatile("global_store_dword %0, %1, off sc0 sc1" :: "v"(p), "v"(v));
}

// wave-parallel poll: lane i watches sp[0] (caller passes base+lane).
// Only wave 0 (or update waves for the rare ring check) runs this.
__device__ __forceinline__ void poll64(const int* sp, int target) {
    int v;
    for (;;) {
        ld4cv(v, sp);
        asm volatile("s_waitcnt vmcnt(0)" : "+v"(v));
        if (__all(v >= target)) return;
        __builtin_amdgcn_s_sleep(2);
    }
}

// ---------------------------------------------------------------------------
// pack_w: fp32 weights -> fp16 B-fragments for mfma_f32_16x16x32_f16.
// B-frag layout: lane holds B[k = ktg*32 + (lane>>4)*8 + j][n = nt*1024 + wg*16 + (lane&15)]
// ktg = i*4 + w (K interleaved across waves). l=0: k in [512,1024) is zero pad.
// ---------------------------------------------------------------------------
__global__ __launch_bounds__(256) void pack_w(
    const float* __restrict__ Wx0, const float* __restrict__ Wh0,
    const float* __restrict__ Wx,  const float* __restrict__ Wh,
    uint32_t* __restrict__ dst)
{
    unsigned g = blockIdx.x * 256u + threadIdx.x;        // < 16,777,216
    unsigned lwg = g >> 16;
    int l = lwg >> 6, wg = lwg & 63;
    unsigned s = g & 65535u;
    int w  = s >> 14, i = (s >> 10) & 15, nt = (s >> 8) & 3;
    int q  = (s >> 6) & 3, jp = (s >> 4) & 3, r = s & 15;
    int k  = (i * 4 + w) * 32 + q * 8 + jp * 2;
    int n  = nt * 1024 + wg * 16 + r;

    float a, bv;
    if (l == 0) {
        if (k < 512)       { a = Wx0[(size_t)k * NG + n]; bv = Wx0[(size_t)(k + 1) * NG + n]; }
        else if (k < 1024) { a = 0.f; bv = 0.f; }
        else               { a = Wh0[(size_t)(k - 1024) * NG + n]; bv = Wh0[(size_t)(k - 1023) * NG + n]; }
    } else {
        const float* src;
        if (k < 1024) src = Wx + (size_t)(l - 1) * H * NG;
        else          src = Wh + (size_t)(l - 1) * H * NG - (size_t)1024 * NG;
        a  = src[(size_t)k * NG + n];
        bv = src[(size_t)(k + 1) * NG + n];
    }
    union { _Float16 h[2]; uint32_t u; } cv;
    cv.h[0] = (_Float16)a; cv.h[1] = (_Float16)bv;
    dst[(size_t)lwg * 65536 + (((size_t)(w * 16 + i) * 4 + nt) * 64 + q * 16 + r) * 4 + jp] = cv.u;
}

// ---------------------------------------------------------------------------
// tile_x: x fp32 [B][T][D_IN] -> Xt fp16 tiled [t][ktg][q][m][8]
// ---------------------------------------------------------------------------
__global__ __launch_bounds__(256) void tile_x(const float* __restrict__ x,
                                              uint32_t* __restrict__ dst)
{
    unsigned g = blockIdx.x * 256u + threadIdx.x;        // < 4,194,304
    int jp = g & 3, m = (g >> 2) & 31, q = (g >> 7) & 3, ktg = (g >> 9) & 15, t = g >> 13;
    int k = ktg * 32 + q * 8 + jp * 2;
    const float* xp = x + (size_t)m * (T * D_IN) + (size_t)t * D_IN + k;
    union { _Float16 h[2]; uint32_t u; } cv;
    cv.h[0] = (_Float16)xp[0]; cv.h[1] = (_Float16)xp[1];
    dst[g] = cv.u;
}

// ---------------------------------------------------------------------------
// Persistent MFMA LSTM. 256 blocks (4 layers x 64 wgs) x 256 threads.
// R6 = R3 (verified passing) + ONE change: late PB-snapshot sampling.
//   R3 sampled the own-layer snapshot v0 at end of step t-1 -- simultaneous
//   with its own flag store, so peers' flags were never visible yet and the
//   PB gate dropped into poll64 EVERY step (+1 IC RT + sleep quantum).
//   R6 issues the v0 sample mid-phase-A of step t (rides the A-load burst,
//   ~2-3us after peers' flag stores) -> fast path actually hits.
//   Safety: identical snapshot->check->poll-fallback structure (stale
//   sample only causes a poll, never a stale read); counted-WAITV budgets
//   re-derived with the extra in-flight load -- conservative in all cases;
//   gate (a)'s v2 wait widened vmcnt(1)->vmcnt(0) (strictly safer).
// Everything else byte-identical to R3 (release mechanism: wave-0 observes
// global flag -> __syncthreads -> all waves load; drain-then-flag publish).
// ---------------------------------------------------------------------------
__global__ __launch_bounds__(256, 1) void lstm_mfma(
    const float* __restrict__ b0,
    const float* __restrict__ bb,
    const float* __restrict__ Wout,
    const float* __restrict__ bout,
    float* __restrict__ out,
    const char* __restrict__ WpkB,
    const char* __restrict__ XtB,
    char* __restrict__ RtB,
    int*   __restrict__ seq)
{
    __shared__ floatx4 red[2048];        // [w][mt][nt][lane][4f32] = 32 KB
    // + 56 KB dynamic LDS (unused) forces 1 block/CU

    const int tid  = threadIdx.x;
    const int l    = blockIdx.x >> 6;
    const int wg   = blockIdx.x & 63;
    const int lane = tid & 63;
    const int w    = tid >> 6;
    const int q    = lane >> 4;
    const int r    = lane & 15;
    const int laneoff = q * 512 + r * 16;

    // ---- one-time: B-fragments into registers ----
    half8 bfr[16][4];
    {
        const half8* wb = (const half8*)WpkB + (size_t)(l * 64 + wg) * 16384 + w * 4096 + lane;
        #pragma unroll
        for (int i = 0; i < 16; ++i)
            #pragma unroll
            for (int nt = 0; nt < 4; ++nt)
                bfr[i][nt] = wb[(i * 4 + nt) * 64];
    }
    // l==0: bfr[4..7] are zeros from pack_w and unused (pad tiles skipped)

    // ---- biases + persistent cell state (update threads: tid<128) ----
    float bias4[4] = {0.f, 0.f, 0.f, 0.f};
    float cst[4]   = {0.f, 0.f, 0.f, 0.f};
    const float* biasl = (l == 0) ? b0 : (bb + (size_t)(l - 1) * NG);
    if (tid < 128) {
        #pragma unroll
        for (int g = 0; g < 4; ++g) bias4[g] = biasl[g * 1024 + wg * 16 + (tid & 15)];
    }

    const int* seqm1 = seq + (l - 1) * 64 + lane;   // valid only l>0
    const int* seq0  = seq + l * 64 + lane;
    const int* seqp1 = seq + (l + 1) * 64 + lane;   // valid only l<L-1

    // cond snapshots: v2 (PA gate) wave 0; v0 (PB gate) wave 0, sampled
    // mid-phase-A each step; v3 (ring gate) update waves
    int v0 = 0, v2 = 0, v3 = 0;
    if (tid < 64 && l > 0) ld4cv(v2, seqm1);

    #define ISSUE4(jj, base, LDF) do { \
        const char* p0_ = (base) + (2*(jj)) * 8192; \
        const char* p1_ = (base) + (2*(jj)+1) * 8192; \
        LDF(ab[jj][0], p0_); LDF(ab[jj][1], p0_ + 256); \
        LDF(ab[jj][2], p1_); LDF(ab[jj][3], p1_ + 256); \
    } while (0)

    #define WAITV(N, jj) asm volatile("s_waitcnt vmcnt(" #N ")" \
        : "+v"(ab[jj][0]), "+v"(ab[jj][1]), "+v"(ab[jj][2]), "+v"(ab[jj][3]))

    #define MFMA4(jj, bi) do { \
        _Pragma("unroll") \
        for (int nt = 0; nt < 4; ++nt) { \
            acc[0][nt] = __builtin_amdgcn_mfma_f32_16x16x32_f16(ab[jj][0], bfr[(bi)][nt],   acc[0][nt], 0, 0, 0); \
            acc[1][nt] = __builtin_amdgcn_mfma_f32_16x16x32_f16(ab[jj][1], bfr[(bi)][nt],   acc[1][nt], 0, 0, 0); \
            acc[0][nt] = __builtin_amdgcn_mfma_f32_16x16x32_f16(ab[jj][2], bfr[(bi)+1][nt], acc[0][nt], 0, 0, 0); \
            acc[1][nt] = __builtin_amdgcn_mfma_f32_16x16x32_f16(ab[jj][3], bfr[(bi)+1][nt], acc[1][nt], 0, 0, 0); \
        } \
    } while (0)

    for (int t = 0; t < T; ++t) {
        half8 ab[4][4];
        floatx4 acc[2][4];
        #pragma unroll
        for (int mt = 0; mt < 2; ++mt)
            #pragma unroll
            for (int nt = 0; nt < 4; ++nt) acc[mt][nt] = (floatx4)0.f;

        // ---------- phase A: input half (no own-h dependency) ----------
        if (l == 0) {
            // Xt constant -> plain cached loads; zero-pad k-tiles skipped.
            const char* axb = XtB + (size_t)t * 32768 + w * 2048 + laneoff;
            ISSUE4(0, axb, ld16nc); ISSUE4(1, axb, ld16nc);
            if (tid < 64) ld4cv(v0, seq0);    // late PB snapshot (R6 diff)
            // queue (wave 0): [flag-ack, 8 loads, v0]; vmcnt(4) drains 6 >= 4
            WAITV(4, 0); MFMA4(0, 0);
            WAITV(0, 1); MFMA4(1, 2);
        } else {
            // gate (a): lower layer published h(t). Wave 0 checks snapshot
            // (conservative on misfire -> poll), barrier releases the rest.
            if (tid < 64) {
                asm volatile("s_waitcnt vmcnt(0)" : "+v"(v2));
                if (!__all(v2 >= t + 1)) poll64(seqm1, t + 1);
            }
            __syncthreads();
            const char* axb = RtB + (size_t)((l - 1) * 8 + slot(t)) * 65536 + w * 2048 + laneoff;
            ISSUE4(0, axb, ld16); ISSUE4(1, axb, ld16);
            ISSUE4(2, axb, ld16); ISSUE4(3, axb, ld16);
            if (tid < 64) ld4cv(v0, seq0);    // late PB snapshot (R6 diff)
            // queue (wave 0): [16 loads, v0]; 12->5>=4, 8->9>=8, 4->13>=12
            WAITV(12, 0); MFMA4(0, 0);
            WAITV(8, 1);  MFMA4(1, 2);
            WAITV(4, 2);  MFMA4(2, 4);
            WAITV(0, 3);  MFMA4(3, 6);
        }

        // ---------- gate (b): own layer h(t-1) from all 64 wgs ----------
        if (tid < 64) {
            asm volatile("s_waitcnt vmcnt(0)" : "+v"(v0));
            if (!__all(v0 >= t)) poll64(seq0, t);
        }
        __syncthreads();
        {
            const char* ahb = RtB + (size_t)(l * 8 + slot(t - 1)) * 65536 + w * 2048 + laneoff;
            ISSUE4(0, ahb, ld16); ISSUE4(1, ahb, ld16);
            ISSUE4(2, ahb, ld16); ISSUE4(3, ahb, ld16);
            WAITV(12, 0); MFMA4(0, 8);
            WAITV(8, 1);  MFMA4(1, 10);
            WAITV(4, 2);  MFMA4(2, 12);
            WAITV(0, 3);  MFMA4(3, 14);
        }

        // ---- cross-wave reduce via LDS ----
        #pragma unroll
        for (int mt = 0; mt < 2; ++mt)
            #pragma unroll
            for (int nt = 0; nt < 4; ++nt)
                red[((w * 2 + mt) * 4 + nt) * 64 + lane] = acc[mt][nt];

        // prefetch ring-safety snapshot (consumed by update waves pre-store)
        if (l < L - 1 && tid < 128) ld4cv(v3, seqp1);
        __syncthreads();   // (c)

        // ---- gate sums + cell update + DIRECT h publish (threads 0..127) ----
        if (tid < 128) {
            if (l < L - 1) {
                // slot(t) still holds h(t-8); layer l+1 must be past phase A
                // of step t-8, i.e. seq_{l+1} >= t-RING+1. Snapshot is ~t-1
                // in steady state -> poll essentially never runs.
                asm volatile("s_waitcnt vmcnt(0)" : "+v"(v3));
                if (t >= RING && !__all(v3 >= t - RING + 1)) poll64(seqp1, t - RING + 1);
            }
            const int u = tid & 15, mq = (tid >> 4) & 7, mt = mq >> 2, qq = mq & 3;
            const int lp = qq * 16 + u;
            floatx4 s0 = (floatx4)0.f, s1 = (floatx4)0.f, s2 = (floatx4)0.f, s3 = (floatx4)0.f;
            #pragma unroll
            for (int w2 = 0; w2 < 4; ++w2) {
                s0 += red[((w2 * 2 + mt) * 4 + 0) * 64 + lp];
                s1 += red[((w2 * 2 + mt) * 4 + 1) * 64 + lp];
                s2 += red[((w2 * 2 + mt) * 4 + 2) * 64 + lp];
                s3 += red[((w2 * 2 + mt) * 4 + 3) * 64 + lp];
            }
            // h[m][u] -> ring byte: K=wg>>1 (*2048), Q=(wg&1)*2+(u>>3) (*512),
            // m*16, (u&7)*2  (identical to R1/R3's layout)
            char* hp = RtB + (size_t)(l * 8 + slot(t)) * 65536
                     + (size_t)(wg >> 1) * 2048 + ((wg & 1) * 2 + (u >> 3)) * 512
                     + (u & 7) * 2;
            #pragma unroll
            for (int rr = 0; rr < 4; ++rr) {
                float gi = s0[rr] + bias4[0];
                float gf = s1[rr] + bias4[1];
                float gg = s2[rr] + bias4[2];
                float go = s3[rr] + bias4[3];
                float cn = sigf(gf) * cst[rr] + sigf(gi) * tanhfast(gg);
                cst[rr] = cn;
                float hv = sigf(go) * tanhfast(cn);
                int m = mt * 16 + qq * 4 + rr;
                union { _Float16 h; unsigned short s; } cvh; cvh.h = (_Float16)hv;
                st2(hp + m * 16, (int)cvh.s);
            }
            // full drain (pure vmcnt(0) = proven ordering primitive):
            // this wave's h stores are acked at the coherence point.
            asm volatile("s_waitcnt vmcnt(0)");
        }
        __syncthreads();   // (d) both update waves drained before the flag

        // ---- publish flag + re-snapshot PA gate (wave 0) ----
        if (tid == 0) st4cv(seq + l * 64 + wg, t + 1);
        if (tid < 64 && l > 0) ld4cv(v2, seqm1);   // queue [seqst, v2]
    }

    #undef ISSUE4
    #undef WAITV
    #undef MFMA4

    // ---- output projection (layer-0 blocks) ----
    if (l != 0) return;
    if (tid < 64) poll64(seq + (L - 1) * 64 + lane, T);
    __syncthreads();

    const int b  = blockIdx.x >> 1;
    const int o0 = (blockIdx.x & 1) << 8;
    const char* rt3 = RtB + (size_t)((L - 1) * 8 + slot(T - 1)) * 65536;
    float* hb = (float*)red;
    if (tid < 128) {
        int j0 = tid * 8;
        half8 hv;
        ld16(hv, rt3 + ((j0 >> 5) * 2048 + ((j0 >> 3) & 3) * 512 + b * 16));
        asm volatile("s_waitcnt vmcnt(0)" : "+v"(hv));
        #pragma unroll
        for (int k2 = 0; k2 < 8; ++k2) hb[j0 + k2] = (float)hv[k2];
    }
    __syncthreads();
    const int o = o0 + tid;
    float s = bout[o];
    #pragma unroll 8
    for (int j = 0; j < H; ++j)
        s += hb[j] * Wout[(size_t)j * D_OUT + o];
    out[(size_t)b * D_OUT + o] = s;
}

extern "C" void kernel_launch(void* const* d_in, const int* in_sizes, int n_in,
                              void* d_out, int out_size, void* d_ws, size_t ws_size,
                              hipStream_t stream) {
    const float* x    = (const float*)d_in[0];
    const float* Wx0  = (const float*)d_in[1];
    const float* Wh0  = (const float*)d_in[2];
    const float* b0   = (const float*)d_in[3];
    const float* Wx   = (const float*)d_in[4];
    const float* Wh   = (const float*)d_in[5];
    const float* bb   = (const float*)d_in[6];
    const float* Wout = (const float*)d_in[7];
    const float* bout = (const float*)d_in[8];
    float* out = (float*)d_out;

    char* ws = (char*)d_ws;
    uint32_t* Wpk  = (uint32_t*)(ws + OFF_WPK);
    uint32_t* Xt   = (uint32_t*)(ws + OFF_XT);
    char*     Rt   = ws + OFF_RT;
    int*      seq  = (int*)(ws + OFF_FLG);

    hipMemsetAsync(Rt, 0, 2097152, stream);              // h(-1) = 0
    hipMemsetAsync(seq, 0, L * 64 * sizeof(int), stream);

    pack_w<<<dim3(65536), dim3(256), 0, stream>>>(Wx0, Wh0, Wx, Wh, Wpk);
    tile_x<<<dim3(16384), dim3(256), 0, stream>>>(x, Xt);

    hipFuncSetAttribute(reinterpret_cast<const void*>(&lstm_mfma),
                        hipFuncAttributeMaxDynamicSharedMemorySize, 57344);
    lstm_mfma<<<dim3(256), dim3(256), 57344, stream>>>(
        b0, bb, Wout, bout, out, (const char*)Wpk, (const char*)Xt, Rt, seq);
}